// Round 14
// baseline (1252.262 us; speedup 1.0000x reference)
//
#include <hip/hip_runtime.h>
#include <stdint.h>

#define DEV static __device__ __forceinline__

typedef unsigned short u16;
typedef float  f32x4 __attribute__((ext_vector_type(4)));
typedef short  s16x8 __attribute__((ext_vector_type(8)));
typedef u16    u16x4 __attribute__((ext_vector_type(4)));

#define VMCNT(n) asm volatile("s_waitcnt vmcnt(" #n ")" ::: "memory")
#define BAR() __builtin_amdgcn_s_barrier()
#define MFMA16(d, va, vb) d = __builtin_amdgcn_mfma_f32_16x16x32_bf16(va, vb, d, 0, 0, 0)

// round-to-nearest-even f32 -> bf16 bits
DEV u16 f2bf(float f) {
  uint32_t u = __float_as_uint(f);
  u += 0x7FFFu + ((u >> 16) & 1u);
  return (u16)(u >> 16);
}

// async global->LDS, 16 bytes per lane
DEV void async16(const void* g, void* l) {
  __builtin_amdgcn_global_load_lds(
      (const __attribute__((address_space(1))) void*)g,
      (__attribute__((address_space(3))) void*)l, 16, 0, 0);
}

// ---------------- router ----------------
__global__ void route_zero(int* c) {
  if (threadIdx.x < 8) c[threadIdx.x] = 0;
}
__global__ void route_count(const int* __restrict__ k, int* __restrict__ c, int B) {
  int i = blockIdx.x * blockDim.x + threadIdx.x;
  if (i < B) atomicAdd(&c[k[i]], 1);
}
__global__ void route_scan(int* c) {
  if (threadIdx.x == 0) {
    int s = 0;
    for (int e = 0; e < 4; ++e) { c[8 + e] = s; s += c[e]; }
  }
}
__global__ void route_scatter(const int* __restrict__ k, int* __restrict__ c,
                              int* __restrict__ perm, int B) {
  int i = blockIdx.x * blockDim.x + threadIdx.x;
  if (i < B) {
    int e = k[i];
    int pos = atomicAdd(&c[4 + e], 1);
    perm[c[8 + e] + pos] = i;
  }
}

// ---------------- conversions ----------------
__global__ void cvt_f32_bf16(const float* __restrict__ src, u16* __restrict__ dst, long n4) {
  long i = (long)blockIdx.x * blockDim.x + threadIdx.x;
  long stride = (long)gridDim.x * blockDim.x;
  for (; i < n4; i += stride) {
    f32x4 v = ((const f32x4*)src)[i];
    u16x4 o;
    o.x = f2bf(v.x); o.y = f2bf(v.y); o.z = f2bf(v.z); o.w = f2bf(v.w);
    ((u16x4*)dst)[i] = o;
  }
}

// src [z][R][C] f32  ->  dst [z][C][R] bf16
__global__ void transpose_w(const float* __restrict__ src, u16* __restrict__ dst,
                            int R, int C) {
  __shared__ float t[32][33];
  long base = (long)blockIdx.z * R * C;
  int c0 = blockIdx.x * 32, r0 = blockIdx.y * 32;
  int tx = threadIdx.x, ty = threadIdx.y;  // (32,8)
#pragma unroll
  for (int i = 0; i < 32; i += 8)
    t[ty + i][tx] = src[base + (long)(r0 + ty + i) * C + c0 + tx];
  __syncthreads();
#pragma unroll
  for (int i = 0; i < 32; i += 8)
    dst[base + (long)(c0 + ty + i) * R + r0 + tx] = f2bf(t[tx][ty + i]);
}

// ======== dense GEMM: 128x256 tile, BK=32 double-buffer, 2 blocks/CU ========
// A [M][K] bf16, Bt [N][K] bf16, C = act(A @ Bt^T + bias)
// 256 threads = 4 waves (1M x 4N), per-wave 128x64 output (acc 128 VGPR).
// __launch_bounds__(256,2): 2 waves/SIMD -> 256-VGPR cap (need ~200).
// LDS 48KB = 2 buf x (A 8KB + B 16KB) -> TWO blocks/CU; the two blocks'
// ds_read bursts and MFMA bursts interleave on separate pipes (the 52%
// MfmaUtil plateau of the 1-block kernels is phase serialization).
// 64B rows; swizzle byte ^= (((row>>1)&3)<<4) (round 8: 0 conflicts, correct).
// Per tile: VMCNT(0) [stage(t), issued 1 tile ago]; BAR; stage(t+1 ->
// other buf) [safe: readers of that buf passed BAR]; 12 ds_read; MFMA.

DEV void stgA32(const u16* __restrict__ src, long K, long bm, int k0,
                u16* lds, int tid) {
#pragma unroll
  for (int j = 0; j < 2; ++j) {
    int i = j * 256 + tid;                       // 0..511
    int r = i >> 2;                              // row 0..127
    int p = (i & 3) << 4;                        // phys byte-in-row
    int ke = (p ^ (((r >> 1) & 3) << 4)) >> 1;   // logical k element
    async16(src + (bm + r) * K + k0 + ke, lds + i * 8);
  }
}

DEV void stgB32(const u16* __restrict__ src, long K, long bn, int k0,
                u16* lds, int tid) {
#pragma unroll
  for (int j = 0; j < 4; ++j) {
    int i = j * 256 + tid;                       // 0..1023
    int r = i >> 2;                              // row 0..255
    int p = (i & 3) << 4;
    int ke = (p ^ (((r >> 1) & 3) << 4)) >> 1;
    async16(src + (bn + r) * K + k0 + ke, lds + i * 8);
  }
}

DEV s16x8 ldfrag32(const u16* lds, int row, int lk) {
  int b = (lk << 4) ^ (((row >> 1) & 3) << 4);
  return *(const s16x8*)((const char*)lds + row * 64 + b);
}

template <int RELU, int OUTF32>
__global__ __launch_bounds__(256, 2) void gemm128d(
    const u16* __restrict__ A, const u16* __restrict__ Bt,
    const float* __restrict__ bias, void* __restrict__ Cout, int N, int K) {
  __shared__ u16 Al[2][128 * 32];
  __shared__ u16 Bl[2][256 * 32];
  const int tid = threadIdx.x;
  const int lane = tid & 63;
  const int wc = tid >> 6;  // 4 waves, 1M x 4N
  const int lr = lane & 15, lk = lane >> 4;

  // XCD-aware bijective swizzle (grids all % 8 == 0; guarded)
  const int nby = N >> 8;
  const int nwg = gridDim.x;
  int wg = blockIdx.x;
  if ((nwg & 7) == 0) {
    const int q = nwg >> 3;
    wg = (wg & 7) * q + (wg >> 3);
  }
  const long bm = (long)(wg / nby) << 7;   // 128-row tile
  const long bn = (long)(wg % nby) << 8;   // 256-col tile

  const int nt = K >> 5;
  f32x4 acc[8][4] = {};

  // prologue: stage tile 0 into buf 0
  stgA32(A, K, bm, 0, Al[0], tid);
  stgB32(Bt, K, bn, 0, Bl[0], tid);

  for (int t = 0; t < nt; ++t) {
    VMCNT(0);  // stage(t) landed (own 6 loads; BAR extends cross-wave)
    BAR();
    const int kn = ((t + 1 < nt) ? t + 1 : t) << 5;  // clamped re-stage: other buf, benign
    stgA32(A, K, bm, kn, Al[(t + 1) & 1], tid);
    stgB32(Bt, K, bn, kn, Bl[(t + 1) & 1], tid);
    const u16* Ac = Al[t & 1];
    const u16* Bc = Bl[t & 1];
    s16x8 a[8], b[4];
#pragma unroll
    for (int m = 0; m < 8; ++m)
      a[m] = ldfrag32(Ac, m * 16 + lr, lk);
#pragma unroll
    for (int n = 0; n < 4; ++n)
      b[n] = ldfrag32(Bc, wc * 64 + n * 16 + lr, lk);
    __builtin_amdgcn_s_setprio(1);
#pragma unroll
    for (int m = 0; m < 8; ++m)
#pragma unroll
      for (int n = 0; n < 4; ++n)
        MFMA16(acc[m][n], a[m], b[n]);
    __builtin_amdgcn_s_setprio(0);
  }

  // epilogue: bias + activation + store
#pragma unroll
  for (int m = 0; m < 8; ++m) {
    const long r0 = bm + m * 16 + lk * 4;
#pragma unroll
    for (int n = 0; n < 4; ++n) {
      const long col = bn + wc * 64 + n * 16 + lr;
      const float bv = bias[col];
#pragma unroll
      for (int j = 0; j < 4; ++j) {
        float v = acc[m][n][j] + bv;
        if (RELU) v = fmaxf(v, 0.0f);
        if (OUTF32) ((float*)Cout)[(r0 + j) * (long)N + col] = v;
        else        ((u16*)Cout)[(r0 + j) * (long)N + col] = f2bf(v);
      }
    }
  }
}

// ======== gathered expert GEMM: round-9 verified 256^2 8-phase ========
DEV void stageB(const u16* __restrict__ Bt, long K, long bn, int k0, int g,
                u16* lds, int tid) {
#pragma unroll
  for (int j = 0; j < 2; ++j) {
    int i = j * 512 + tid;
    int col = ((i >> 8) << 6) | (g << 5) | ((i >> 3) & 31);
    int p = (i & 7) * 16;
    int ke = (p ^ ((col & 7) << 4)) >> 1;
    async16(Bt + (bn + col) * K + k0 + ke, lds + col * 64 + (i & 7) * 8);
  }
}

DEV void stageAg(const u16* __restrict__ X, long K, int k0, int g,
                 const long* ar, u16* lds, int tid) {
#pragma unroll
  for (int j = 0; j < 2; ++j) {
    int i = j * 512 + tid;
    int row = (j << 7) | (g << 6) | ((i >> 3) & 63);
    int p = (i & 7) * 16;
    int ke = (p ^ ((row & 7) << 4)) >> 1;
    async16(X + ar[j] * K + k0 + ke, lds + row * 64 + (i & 7) * 8);
  }
}

DEV s16x8 ldfrag(const u16* lds, int row, int ks, int lk) {
  int b = (ks * 64 + lk * 16) ^ ((row & 7) << 4);
  return *(const s16x8*)((const char*)(lds + row * 64) + b);
}

// one K-tile = 4 phases (round-9 verified; 1 bar/phase, reads-late)
#define KT4(Ac, Bc, S1, S2, S3, S4)                                            \
  {                                                                            \
    _Pragma("unroll") for (int m = 0; m < 4; ++m)                              \
      _Pragma("unroll") for (int ks = 0; ks < 2; ++ks)                         \
        aa[m][ks] = ldfrag(Ac, wr * 128 + m * 16 + lr, ks, lk);                \
    _Pragma("unroll") for (int n = 0; n < 2; ++n)                              \
      _Pragma("unroll") for (int ks = 0; ks < 2; ++ks)                         \
        blo[n][ks] = ldfrag(Bc, wc * 64 + n * 16 + lr, ks, lk);                \
    S1;                                                                        \
    BAR();                                                                     \
    __builtin_amdgcn_s_setprio(1);                                             \
    _Pragma("unroll") for (int m = 0; m < 4; ++m)                              \
      _Pragma("unroll") for (int n = 0; n < 2; ++n)                            \
        _Pragma("unroll") for (int ks = 0; ks < 2; ++ks)                       \
          MFMA16(acc[m][n], aa[m][ks], blo[n][ks]);                            \
    __builtin_amdgcn_s_setprio(0);                                             \
    _Pragma("unroll") for (int n = 0; n < 2; ++n)                              \
      _Pragma("unroll") for (int ks = 0; ks < 2; ++ks)                         \
        bhi[n][ks] = ldfrag(Bc, wc * 64 + (n + 2) * 16 + lr, ks, lk);          \
    S2;                                                                        \
    BAR();                                                                     \
    __builtin_amdgcn_s_setprio(1);                                             \
    _Pragma("unroll") for (int m = 0; m < 4; ++m)                              \
      _Pragma("unroll") for (int n = 0; n < 2; ++n)                            \
        _Pragma("unroll") for (int ks = 0; ks < 2; ++ks)                       \
          MFMA16(acc[m][n + 2], aa[m][ks], bhi[n][ks]);                        \
    __builtin_amdgcn_s_setprio(0);                                             \
    _Pragma("unroll") for (int m = 0; m < 4; ++m)                              \
      _Pragma("unroll") for (int ks = 0; ks < 2; ++ks)                         \
        aa[m][ks] = ldfrag(Ac, wr * 128 + (m + 4) * 16 + lr, ks, lk);          \
    S3;                                                                        \
    BAR();                                                                     \
    __builtin_amdgcn_s_setprio(1);                                             \
    _Pragma("unroll") for (int m = 0; m < 4; ++m)                              \
      _Pragma("unroll") for (int n = 0; n < 2; ++n)                            \
        _Pragma("unroll") for (int ks = 0; ks < 2; ++ks)                       \
          MFMA16(acc[m + 4][n], aa[m][ks], blo[n][ks]);                        \
    __builtin_amdgcn_s_setprio(0);                                             \
    S4;                                                                        \
    VMCNT(6);                                                                  \
    BAR();                                                                     \
    __builtin_amdgcn_s_setprio(1);                                             \
    _Pragma("unroll") for (int m = 0; m < 4; ++m)                              \
      _Pragma("unroll") for (int n = 0; n < 2; ++n)                            \
        _Pragma("unroll") for (int ks = 0; ks < 2; ++ks)                       \
          MFMA16(acc[m + 4][n + 2], aa[m][ks], bhi[n][ks]);                    \
    __builtin_amdgcn_s_setprio(0);                                             \
  }

__global__ __launch_bounds__(512, 2) void gemm256e(
    const u16* __restrict__ X, const u16* __restrict__ Wt,
    const float* __restrict__ bexp, u16* __restrict__ Out,
    const int* __restrict__ perm, const int* __restrict__ cvec,
    int K, int N, int TPE) {
  __shared__ u16 Al[2][256 * 64];
  __shared__ u16 Bl[2][256 * 64];
  const int e = blockIdx.x / TPE;
  const int tile = blockIdx.x - e * TPE;
  const int cnt = cvec[e];
  if (tile * 256 >= cnt) return;
  const int start = cvec[8 + e];

  const int tid = threadIdx.x;
  const int lane = tid & 63, wid = tid >> 6;
  const int wr = wid >> 2, wc = wid & 3;  // 2M x 4N
  const int lr = lane & 15, lk = lane >> 4;
  const long bn = (long)blockIdx.y << 8;
  const long wbase = (long)e * N;

  // preload gathered A-row indices (fixed per thread)
  long ar[2][2];
#pragma unroll
  for (int g = 0; g < 2; ++g)
#pragma unroll
    for (int j = 0; j < 2; ++j) {
      int rie = tile * 256 + ((j << 7) | (g << 6) | ((tid >> 3) & 63));
      ar[g][j] = perm[start + (rie < cnt - 1 ? rie : cnt - 1)];
    }

  const int nt = K >> 6;  // K=2048 -> 32, even
  f32x4 acc[8][4] = {};
  s16x8 aa[4][2], blo[2][2], bhi[2][2];

  stageAg(X, K, 0, 0, ar[0], Al[0], tid);
  stageB(Wt, K, wbase + bn, 0, 0, Bl[0], tid);
  stageB(Wt, K, wbase + bn, 0, 1, Bl[0], tid);
  stageAg(X, K, 0, 1, ar[1], Al[0], tid);
  stageAg(X, K, 64, 0, ar[0], Al[1], tid);
  stageB(Wt, K, wbase + bn, 64, 0, Bl[1], tid);
  stageB(Wt, K, wbase + bn, 64, 1, Bl[1], tid);
  VMCNT(6);
  BAR();

  const int ni = nt >> 1;
  for (int i2 = 0; i2 < ni; ++i2) {
    const int t0 = 2 * i2;
    const int kn1 = (t0 + 1) << 6;
    const int kn2 = ((t0 + 2 < nt) ? t0 + 2 : t0) << 6;
    const int kn3 = ((t0 + 3 < nt) ? t0 + 3 : t0 + 1) << 6;
    KT4(Al[0], Bl[0],
        stageAg(X, K, kn1, 1, ar[1], Al[1], tid),
        stageAg(X, K, kn2, 0, ar[0], Al[0], tid),
        stageB(Wt, K, wbase + bn, kn2, 0, Bl[0], tid),
        stageB(Wt, K, wbase + bn, kn2, 1, Bl[0], tid));
    KT4(Al[1], Bl[1],
        stageAg(X, K, kn2, 1, ar[1], Al[0], tid),
        stageAg(X, K, kn3, 0, ar[0], Al[1], tid),
        stageB(Wt, K, wbase + bn, kn3, 0, Bl[1], tid),
        stageB(Wt, K, wbase + bn, kn3, 1, Bl[1], tid));
  }

  // epilogue: bias + scatter via perm (guard rb < cnt) — FULL m 0..7
#pragma unroll
  for (int m = 0; m < 8; ++m) {
    const int rb = tile * 256 + wr * 128 + m * 16 + lk * 4;
#pragma unroll
    for (int j = 0; j < 4; ++j) {
      if (rb + j < cnt) {
        const long grow = perm[start + rb + j];
#pragma unroll
        for (int n = 0; n < 4; ++n) {
          const long col = bn + wc * 64 + n * 16 + lr;
          float v = acc[m][n][j] + bexp[wbase + col];
          Out[grow * (long)N + col] = f2bf(v);
        }
      }
    }
  }
}

// ---------------- launch ----------------
extern "C" void kernel_launch(void* const* d_in, const int* in_sizes, int n_in,
                              void* d_out, int out_size, void* d_ws, size_t ws_size,
                              hipStream_t stream) {
  const float* x     = (const float*)d_in[0];
  const int*   kk    = (const int*)d_in[1];
  const float* W_exp = (const float*)d_in[2];
  const float* b_exp = (const float*)d_in[3];
  const float* W1    = (const float*)d_in[4];
  const float* b1    = (const float*)d_in[5];
  const float* W2    = (const float*)d_in[6];
  const float* b2    = (const float*)d_in[7];
  const float* W3    = (const float*)d_in[8];
  const float* b3    = (const float*)d_in[9];
  float* out = (float*)d_out;

  const int B = 16384, DIN = 2048, DC = 1024, H = 4096, DOUT = 1024, E = 4;

  uint8_t* ws = (uint8_t*)d_ws;
  const size_t MB = 1ull << 20;
  u16* xb    = (u16*)(ws + 0);         // 64MB  [B][2048]
  u16* algn  = (u16*)(ws + 64 * MB);   // 32MB  [B][1024]
  u16* h2    = (u16*)(ws + 0);         // 128MB [B][4096] (reuses xb+algn, live later)
  u16* h1    = (u16*)(ws + 128 * MB);  // 128MB [B][4096]
  u16* wexpt = (u16*)(ws + 256 * MB);  // 16MB  [4][1024][2048]
  u16* w1t   = (u16*)(ws + 272 * MB);  // 8MB   [4096][1024]
  u16* w2t   = (u16*)(ws + 280 * MB);  // 32MB  [4096][4096]
  u16* w3t   = (u16*)(ws + 312 * MB);  // 8MB   [1024][4096]
  int* perm  = (int*)(ws + 320 * MB);  // 64KB
  int* cvec  = (int*)(ws + 320 * MB + 65536);

  // router
  route_zero<<<1, 64, 0, stream>>>(cvec);
  route_count<<<(B + 255) / 256, 256, 0, stream>>>(kk, cvec, B);
  route_scan<<<1, 64, 0, stream>>>(cvec);
  route_scatter<<<(B + 255) / 256, 256, 0, stream>>>(kk, cvec, perm, B);

  // conversions
  cvt_f32_bf16<<<2048, 256, 0, stream>>>(x, xb, (long)B * DIN / 4);
  dim3 tb(32, 8);
  transpose_w<<<dim3(DC / 32, DIN / 32, E), tb, 0, stream>>>(W_exp, wexpt, DIN, DC);
  transpose_w<<<dim3(H / 32, DC / 32, 1), tb, 0, stream>>>(W1, w1t, DC, H);
  transpose_w<<<dim3(H / 32, H / 32, 1), tb, 0, stream>>>(W2, w2t, H, H);
  transpose_w<<<dim3(DOUT / 32, H / 32, 1), tb, 0, stream>>>(W3, w3t, H, DOUT);

  // expert projection (round-9 verified 256^2 8-phase)
  const int TPE = B / 256;
  gemm256e<<<dim3(E * TPE, DC / 256), 512, 0, stream>>>(
      xb, wexpt, b_exp, algn, perm, cvec, DIN, DC, TPE);

  // dense MLP on 128x256 double-buffer 2-blocks/CU kernel
  gemm128d<1, 0><<<dim3((B / 128) * (H / 256)), 256, 0, stream>>>(algn, w1t, b1, h1, H, DC);
  gemm128d<1, 0><<<dim3((B / 128) * (H / 256)), 256, 0, stream>>>(h1, w2t, b2, h2, H, H);
  gemm128d<0, 1><<<dim3((B / 128) * (DOUT / 256)), 256, 0, stream>>>(h2, w3t, b3, out, DOUT, H);
}

// Round 15
// 1063.049 us; speedup vs baseline: 1.1780x; 1.1780x over previous
//
#include <hip/hip_runtime.h>
#include <stdint.h>

#define DEV static __device__ __forceinline__

typedef unsigned short u16;
typedef float  f32x4 __attribute__((ext_vector_type(4)));
typedef short  s16x8 __attribute__((ext_vector_type(8)));
typedef u16    u16x4 __attribute__((ext_vector_type(4)));

#define VMCNT(n) asm volatile("s_waitcnt vmcnt(" #n ")" ::: "memory")
#define BAR() __builtin_amdgcn_s_barrier()
#define MFMA16(d, va, vb) d = __builtin_amdgcn_mfma_f32_16x16x32_bf16(va, vb, d, 0, 0, 0)

// round-to-nearest-even f32 -> bf16 bits
DEV u16 f2bf(float f) {
  uint32_t u = __float_as_uint(f);
  u += 0x7FFFu + ((u >> 16) & 1u);
  return (u16)(u >> 16);
}

// async global->LDS, 16 bytes per lane
DEV void async16(const void* g, void* l) {
  __builtin_amdgcn_global_load_lds(
      (const __attribute__((address_space(1))) void*)g,
      (__attribute__((address_space(3))) void*)l, 16, 0, 0);
}

// ---------------- router ----------------
__global__ void route_zero(int* c) {
  if (threadIdx.x < 8) c[threadIdx.x] = 0;
}
__global__ void route_count(const int* __restrict__ k, int* __restrict__ c, int B) {
  int i = blockIdx.x * blockDim.x + threadIdx.x;
  if (i < B) atomicAdd(&c[k[i]], 1);
}
__global__ void route_scan(int* c) {
  if (threadIdx.x == 0) {
    int s = 0;
    for (int e = 0; e < 4; ++e) { c[8 + e] = s; s += c[e]; }
  }
}
__global__ void route_scatter(const int* __restrict__ k, int* __restrict__ c,
                              int* __restrict__ perm, int B) {
  int i = blockIdx.x * blockDim.x + threadIdx.x;
  if (i < B) {
    int e = k[i];
    int pos = atomicAdd(&c[4 + e], 1);
    perm[c[8 + e] + pos] = i;
  }
}

// ---------------- conversions ----------------
__global__ void cvt_f32_bf16(const float* __restrict__ src, u16* __restrict__ dst, long n4) {
  long i = (long)blockIdx.x * blockDim.x + threadIdx.x;
  long stride = (long)gridDim.x * blockDim.x;
  for (; i < n4; i += stride) {
    f32x4 v = ((const f32x4*)src)[i];
    u16x4 o;
    o.x = f2bf(v.x); o.y = f2bf(v.y); o.z = f2bf(v.z); o.w = f2bf(v.w);
    ((u16x4*)dst)[i] = o;
  }
}

// src [z][R][C] f32  ->  dst [z][C][R] bf16
__global__ void transpose_w(const float* __restrict__ src, u16* __restrict__ dst,
                            int R, int C) {
  __shared__ float t[32][33];
  long base = (long)blockIdx.z * R * C;
  int c0 = blockIdx.x * 32, r0 = blockIdx.y * 32;
  int tx = threadIdx.x, ty = threadIdx.y;  // (32,8)
#pragma unroll
  for (int i = 0; i < 32; i += 8)
    t[ty + i][tx] = src[base + (long)(r0 + ty + i) * C + c0 + tx];
  __syncthreads();
#pragma unroll
  for (int i = 0; i < 32; i += 8)
    dst[base + (long)(c0 + ty + i) * R + r0 + tx] = f2bf(t[tx][ty + i]);
}

// ======== 256x256 uniform-stage 8-phase / 2-K-tile GEMM (round-9 verified) ========
// 512 threads = 8 waves (2M x 4N), per-wave 128x64. BK=64. LDS 128KB.
// Rows 128B, XOR swizzle byte ^= (row&7)<<4 (inverse on global source);
// 0 bank conflicts measured. Stage schedule: P1 Ah1(t+1), P2 Ah0(t+2),
// P3 Bh0(t+2), P4 Bh1(t+2)+vmcnt(6), mirrored for second K-tile.

DEV void stageA(const u16* __restrict__ A, long K, long bm, int k0, int g,
                u16* lds, int tid) {
#pragma unroll
  for (int j = 0; j < 2; ++j) {
    int i = j * 512 + tid;
    int row = ((i >> 9) << 7) | (g << 6) | ((i >> 3) & 63);
    int p = (i & 7) * 16;                  // phys byte-in-row
    int ke = (p ^ ((row & 7) << 4)) >> 1;  // logical k element (inverse swizzle)
    async16(A + (bm + row) * K + k0 + ke, lds + row * 64 + (i & 7) * 8);
  }
}

DEV void stageB(const u16* __restrict__ Bt, long K, long bn, int k0, int g,
                u16* lds, int tid) {
#pragma unroll
  for (int j = 0; j < 2; ++j) {
    int i = j * 512 + tid;
    int col = ((i >> 8) << 6) | (g << 5) | ((i >> 3) & 31);
    int p = (i & 7) * 16;
    int ke = (p ^ ((col & 7) << 4)) >> 1;
    async16(Bt + (bn + col) * K + k0 + ke, lds + col * 64 + (i & 7) * 8);
  }
}

// gathered A staging: per-thread global rows preloaded (ar[j]), LDS row from tid
DEV void stageAg(const u16* __restrict__ X, long K, int k0, int g,
                 const long* ar, u16* lds, int tid) {
#pragma unroll
  for (int j = 0; j < 2; ++j) {
    int i = j * 512 + tid;
    int row = (j << 7) | (g << 6) | ((i >> 3) & 63);
    int p = (i & 7) * 16;
    int ke = (p ^ ((row & 7) << 4)) >> 1;
    async16(X + ar[j] * K + k0 + ke, lds + row * 64 + (i & 7) * 8);
  }
}

DEV s16x8 ldfrag(const u16* lds, int row, int ks, int lk) {
  int b = (ks * 64 + lk * 16) ^ ((row & 7) << 4);
  return *(const s16x8*)((const char*)(lds + row * 64) + b);
}

// one K-tile = 4 phases; S1..S4 = per-phase stage statements; 1 bar/phase
#define KT4(Ac, Bc, S1, S2, S3, S4)                                            \
  {                                                                            \
    _Pragma("unroll") for (int m = 0; m < 4; ++m)                              \
      _Pragma("unroll") for (int ks = 0; ks < 2; ++ks)                         \
        aa[m][ks] = ldfrag(Ac, wr * 128 + m * 16 + lr, ks, lk);                \
    _Pragma("unroll") for (int n = 0; n < 2; ++n)                              \
      _Pragma("unroll") for (int ks = 0; ks < 2; ++ks)                         \
        blo[n][ks] = ldfrag(Bc, wc * 64 + n * 16 + lr, ks, lk);                \
    S1;                                                                        \
    BAR();                                                                     \
    __builtin_amdgcn_s_setprio(1);                                             \
    _Pragma("unroll") for (int m = 0; m < 4; ++m)                              \
      _Pragma("unroll") for (int n = 0; n < 2; ++n)                            \
        _Pragma("unroll") for (int ks = 0; ks < 2; ++ks)                       \
          MFMA16(acc[m][n], aa[m][ks], blo[n][ks]);                            \
    __builtin_amdgcn_s_setprio(0);                                             \
    _Pragma("unroll") for (int n = 0; n < 2; ++n)                              \
      _Pragma("unroll") for (int ks = 0; ks < 2; ++ks)                         \
        bhi[n][ks] = ldfrag(Bc, wc * 64 + (n + 2) * 16 + lr, ks, lk);          \
    S2;                                                                        \
    BAR();                                                                     \
    __builtin_amdgcn_s_setprio(1);                                             \
    _Pragma("unroll") for (int m = 0; m < 4; ++m)                              \
      _Pragma("unroll") for (int n = 0; n < 2; ++n)                            \
        _Pragma("unroll") for (int ks = 0; ks < 2; ++ks)                       \
          MFMA16(acc[m][n + 2], aa[m][ks], bhi[n][ks]);                        \
    __builtin_amdgcn_s_setprio(0);                                             \
    _Pragma("unroll") for (int m = 0; m < 4; ++m)                              \
      _Pragma("unroll") for (int ks = 0; ks < 2; ++ks)                         \
        aa[m][ks] = ldfrag(Ac, wr * 128 + (m + 4) * 16 + lr, ks, lk);          \
    S3;                                                                        \
    BAR();                                                                     \
    __builtin_amdgcn_s_setprio(1);                                             \
    _Pragma("unroll") for (int m = 0; m < 4; ++m)                              \
      _Pragma("unroll") for (int n = 0; n < 2; ++n)                            \
        _Pragma("unroll") for (int ks = 0; ks < 2; ++ks)                       \
          MFMA16(acc[m + 4][n], aa[m][ks], blo[n][ks]);                        \
    __builtin_amdgcn_s_setprio(0);                                             \
    S4;                                                                        \
    VMCNT(6);                                                                  \
    BAR();                                                                     \
    __builtin_amdgcn_s_setprio(1);                                             \
    _Pragma("unroll") for (int m = 0; m < 4; ++m)                              \
      _Pragma("unroll") for (int n = 0; n < 2; ++n)                            \
        _Pragma("unroll") for (int ks = 0; ks < 2; ++ks)                       \
          MFMA16(acc[m + 4][n + 2], aa[m][ks], bhi[n][ks]);                    \
    __builtin_amdgcn_s_setprio(0);                                             \
  }

template <int RELU, int OUTF32>
__global__ __launch_bounds__(512, 2) void gemm256p(
    const u16* __restrict__ A, const u16* __restrict__ Bt,
    const float* __restrict__ bias, void* __restrict__ Cout, int N, int K) {
  __shared__ u16 Al[2][256 * 64];
  __shared__ u16 Bl[2][256 * 64];
  const int tid = threadIdx.x;
  const int lane = tid & 63, wid = tid >> 6;
  const int wr = wid >> 2, wc = wid & 3;  // 2 x 4 wave grid
  const int lr = lane & 15, lk = lane >> 4;

  // XCD-aware bijective swizzle (grids all % 8 == 0; guarded)
  const int nby = N >> 8;
  const int nwg = gridDim.x;
  int wg = blockIdx.x;
  if ((nwg & 7) == 0) {
    const int q = nwg >> 3;
    wg = (wg & 7) * q + (wg >> 3);
  }
  const long bm = (long)(wg / nby) << 8;
  const long bn = (long)(wg % nby) << 8;

  const int nt = K >> 6;  // even (>=16) for all K used here
  f32x4 acc[8][4] = {};
  s16x8 aa[4][2], blo[2][2], bhi[2][2];

  // prologue: tile0 fully + tile1 halves Ah0,Bh0,Bh1 (Ah1(1) staged at P1)
  stageA(A, K, bm, 0, 0, Al[0], tid);
  stageB(Bt, K, bn, 0, 0, Bl[0], tid);
  stageB(Bt, K, bn, 0, 1, Bl[0], tid);
  stageA(A, K, bm, 0, 1, Al[0], tid);
  stageA(A, K, bm, 64, 0, Al[1], tid);
  stageB(Bt, K, bn, 64, 0, Bl[1], tid);
  stageB(Bt, K, bn, 64, 1, Bl[1], tid);
  VMCNT(6);  // drains tile0's 8 loads; leaves tile1's 3 halves (steady state)
  BAR();

  const int ni = nt >> 1;
  for (int i2 = 0; i2 < ni; ++i2) {
    const int t0 = 2 * i2;
    const int kn1 = (t0 + 1) << 6;  // fresh stage of Ah1(t+1)
    const int kn2 = ((t0 + 2 < nt) ? t0 + 2 : t0) << 6;       // clamped re-stage
    const int kn3 = ((t0 + 3 < nt) ? t0 + 3 : t0 + 1) << 6;
    KT4(Al[0], Bl[0],
        stageA(A, K, bm, kn1, 1, Al[1], tid),
        stageA(A, K, bm, kn2, 0, Al[0], tid),
        stageB(Bt, K, bn, kn2, 0, Bl[0], tid),
        stageB(Bt, K, bn, kn2, 1, Bl[0], tid));
    KT4(Al[1], Bl[1],
        stageA(A, K, bm, kn2, 1, Al[0], tid),
        stageA(A, K, bm, kn3, 0, Al[1], tid),
        stageB(Bt, K, bn, kn3, 0, Bl[1], tid),
        stageB(Bt, K, bn, kn3, 1, Bl[1], tid));
  }

  // epilogue: bias + activation + store
#pragma unroll
  for (int m = 0; m < 8; ++m) {
    const long r0 = bm + wr * 128 + m * 16 + lk * 4;
#pragma unroll
    for (int n = 0; n < 4; ++n) {
      const long col = bn + wc * 64 + n * 16 + lr;
      const float bv = bias[col];
#pragma unroll
      for (int j = 0; j < 4; ++j) {
        float v = acc[m][n][j] + bv;
        if (RELU) v = fmaxf(v, 0.0f);
        if (OUTF32) ((float*)Cout)[(r0 + j) * (long)N + col] = v;
        else        ((u16*)Cout)[(r0 + j) * (long)N + col] = f2bf(v);
      }
    }
  }
}

// ======== gathered expert GEMM on the same 256x256 8-phase structure ========
__global__ __launch_bounds__(512, 2) void gemm256e(
    const u16* __restrict__ X, const u16* __restrict__ Wt,
    const float* __restrict__ bexp, u16* __restrict__ Out,
    const int* __restrict__ perm, const int* __restrict__ cvec,
    int K, int N, int TPE) {
  __shared__ u16 Al[2][256 * 64];
  __shared__ u16 Bl[2][256 * 64];
  const int e = blockIdx.x / TPE;
  const int tile = blockIdx.x - e * TPE;
  const int cnt = cvec[e];
  if (tile * 256 >= cnt) return;
  const int start = cvec[8 + e];

  const int tid = threadIdx.x;
  const int lane = tid & 63, wid = tid >> 6;
  const int wr = wid >> 2, wc = wid & 3;  // 2M x 4N
  const int lr = lane & 15, lk = lane >> 4;
  const long bn = (long)blockIdx.y << 8;
  const long wbase = (long)e * N;

  // preload gathered A-row indices (fixed per thread)
  long ar[2][2];
#pragma unroll
  for (int g = 0; g < 2; ++g)
#pragma unroll
    for (int j = 0; j < 2; ++j) {
      int rie = tile * 256 + ((j << 7) | (g << 6) | ((tid >> 3) & 63));
      ar[g][j] = perm[start + (rie < cnt - 1 ? rie : cnt - 1)];
    }

  const int nt = K >> 6;  // K=2048 -> 32, even
  f32x4 acc[8][4] = {};
  s16x8 aa[4][2], blo[2][2], bhi[2][2];

  stageAg(X, K, 0, 0, ar[0], Al[0], tid);
  stageB(Wt, K, wbase + bn, 0, 0, Bl[0], tid);
  stageB(Wt, K, wbase + bn, 0, 1, Bl[0], tid);
  stageAg(X, K, 0, 1, ar[1], Al[0], tid);
  stageAg(X, K, 64, 0, ar[0], Al[1], tid);
  stageB(Wt, K, wbase + bn, 64, 0, Bl[1], tid);
  stageB(Wt, K, wbase + bn, 64, 1, Bl[1], tid);
  VMCNT(6);
  BAR();

  const int ni = nt >> 1;
  for (int i2 = 0; i2 < ni; ++i2) {
    const int t0 = 2 * i2;
    const int kn1 = (t0 + 1) << 6;
    const int kn2 = ((t0 + 2 < nt) ? t0 + 2 : t0) << 6;
    const int kn3 = ((t0 + 3 < nt) ? t0 + 3 : t0 + 1) << 6;
    KT4(Al[0], Bl[0],
        stageAg(X, K, kn1, 1, ar[1], Al[1], tid),
        stageAg(X, K, kn2, 0, ar[0], Al[0], tid),
        stageB(Wt, K, wbase + bn, kn2, 0, Bl[0], tid),
        stageB(Wt, K, wbase + bn, kn2, 1, Bl[0], tid));
    KT4(Al[1], Bl[1],
        stageAg(X, K, kn2, 1, ar[1], Al[0], tid),
        stageAg(X, K, kn3, 0, ar[0], Al[1], tid),
        stageB(Wt, K, wbase + bn, kn3, 0, Bl[1], tid),
        stageB(Wt, K, wbase + bn, kn3, 1, Bl[1], tid));
  }

  // epilogue: bias + scatter via perm (guard rb < cnt)
#pragma unroll
  for (int m = 0; m < 8; ++m) {
    const int rb = tile * 256 + wr * 128 + m * 16 + lk * 4;
#pragma unroll
    for (int j = 0; j < 4; ++j) {
      if (rb + j < cnt) {
        const long grow = perm[start + rb + j];
#pragma unroll
        for (int n = 0; n < 4; ++n) {
          const long col = bn + wc * 64 + n * 16 + lr;
          float v = acc[m][n][j] + bexp[wbase + col];
          Out[grow * (long)N + col] = f2bf(v);
        }
      }
    }
  }
}

// ---------------- launch ----------------
extern "C" void kernel_launch(void* const* d_in, const int* in_sizes, int n_in,
                              void* d_out, int out_size, void* d_ws, size_t ws_size,
                              hipStream_t stream) {
  const float* x     = (const float*)d_in[0];
  const int*   kk    = (const int*)d_in[1];
  const float* W_exp = (const float*)d_in[2];
  const float* b_exp = (const float*)d_in[3];
  const float* W1    = (const float*)d_in[4];
  const float* b1    = (const float*)d_in[5];
  const float* W2    = (const float*)d_in[6];
  const float* b2    = (const float*)d_in[7];
  const float* W3    = (const float*)d_in[8];
  const float* b3    = (const float*)d_in[9];
  float* out = (float*)d_out;

  const int B = 16384, DIN = 2048, DC = 1024, H = 4096, DOUT = 1024, E = 4;

  uint8_t* ws = (uint8_t*)d_ws;
  const size_t MB = 1ull << 20;
  u16* xb    = (u16*)(ws + 0);         // 64MB  [B][2048]
  u16* algn  = (u16*)(ws + 64 * MB);   // 32MB  [B][1024]
  u16* h2    = (u16*)(ws + 0);         // 128MB [B][4096] (reuses xb+algn, live later)
  u16* h1    = (u16*)(ws + 128 * MB);  // 128MB [B][4096]
  u16* wexpt = (u16*)(ws + 256 * MB);  // 16MB  [4][1024][2048]
  u16* w1t   = (u16*)(ws + 272 * MB);  // 8MB   [4096][1024]
  u16* w2t   = (u16*)(ws + 280 * MB);  // 32MB  [4096][4096]
  u16* w3t   = (u16*)(ws + 312 * MB);  // 8MB   [1024][4096]
  int* perm  = (int*)(ws + 320 * MB);  // 64KB
  int* cvec  = (int*)(ws + 320 * MB + 65536);

  // router
  route_zero<<<1, 64, 0, stream>>>(cvec);
  route_count<<<(B + 255) / 256, 256, 0, stream>>>(kk, cvec, B);
  route_scan<<<1, 64, 0, stream>>>(cvec);
  route_scatter<<<(B + 255) / 256, 256, 0, stream>>>(kk, cvec, perm, B);

  // conversions
  cvt_f32_bf16<<<2048, 256, 0, stream>>>(x, xb, (long)B * DIN / 4);
  dim3 tb(32, 8);
  transpose_w<<<dim3(DC / 32, DIN / 32, E), tb, 0, stream>>>(W_exp, wexpt, DIN, DC);
  transpose_w<<<dim3(H / 32, DC / 32, 1), tb, 0, stream>>>(W1, w1t, DC, H);
  transpose_w<<<dim3(H / 32, H / 32, 1), tb, 0, stream>>>(W2, w2t, H, H);
  transpose_w<<<dim3(DOUT / 32, H / 32, 1), tb, 0, stream>>>(W3, w3t, H, DOUT);

  // expert projection (gathered, 256^2 8-phase)
  const int TPE = B / 256;
  gemm256e<<<dim3(E * TPE, DC / 256), 512, 0, stream>>>(
      xb, wexpt, b_exp, algn, perm, cvec, DIN, DC, TPE);

  // dense MLP on uniform-stage 8-phase 256^2 kernel (round-9 verified)
  gemm256p<1, 0><<<dim3((B / 256) * (H / 256)), 512, 0, stream>>>(algn, w1t, b1, h1, H, DC);
  gemm256p<1, 0><<<dim3((B / 256) * (H / 256)), 512, 0, stream>>>(h1, w2t, b2, h2, H, H);
  gemm256p<0, 1><<<dim3((B / 256) * (DOUT / 256)), 512, 0, stream>>>(h2, w3t, b3, out, DOUT, H);
}

// Round 16
// 878.829 us; speedup vs baseline: 1.4249x; 1.2096x over previous
//
#include <hip/hip_runtime.h>
#include <stdint.h>

#define DEV static __device__ __forceinline__

typedef unsigned short u16;
typedef float  f32x4 __attribute__((ext_vector_type(4)));
typedef short  s16x8 __attribute__((ext_vector_type(8)));
typedef u16    u16x4 __attribute__((ext_vector_type(4)));

#define VMCNT(n) asm volatile("s_waitcnt vmcnt(" #n ")" ::: "memory")
#define BAR() __builtin_amdgcn_s_barrier()
#define MFMA16(d, va, vb) d = __builtin_amdgcn_mfma_f32_16x16x32_bf16(va, vb, d, 0, 0, 0)

// round-to-nearest-even f32 -> bf16 bits
DEV u16 f2bf(float f) {
  uint32_t u = __float_as_uint(f);
  u += 0x7FFFu + ((u >> 16) & 1u);
  return (u16)(u >> 16);
}

// async global->LDS, 16 bytes per lane
DEV void async16(const void* g, void* l) {
  __builtin_amdgcn_global_load_lds(
      (const __attribute__((address_space(1))) void*)g,
      (__attribute__((address_space(3))) void*)l, 16, 0, 0);
}

// ---------------- fused router (count+scan+scatter, wave-aggregated) ----------------
// cvec layout: [0..3]=cnt, [4..7]=cursor, [8..11]=start
__global__ __launch_bounds__(1024) void route_all(const int* __restrict__ k,
                                                  int* __restrict__ c,
                                                  int* __restrict__ perm, int B) {
  __shared__ int lc[12];
  const int tid = threadIdx.x;
  const int lane = tid & 63;
  if (tid < 12) lc[tid] = 0;
  __syncthreads();
  // count: one atomic per wave per expert value
  for (int i = tid; i < B; i += 1024) {
    int e = k[i];
#pragma unroll
    for (int v = 0; v < 4; ++v) {
      unsigned long long m = __ballot(e == v);
      if (m != 0ull && lane == __ffsll((long long)m) - 1)
        atomicAdd(&lc[v], __popcll(m));
    }
  }
  __syncthreads();
  if (tid == 0) {
    int s = 0;
    for (int e = 0; e < 4; ++e) { lc[8 + e] = s; s += lc[e]; }
  }
  __syncthreads();
  // scatter: wave-aggregated rank, one atomic per wave per value
  for (int i = tid; i < B; i += 1024) {
    int e = k[i];
#pragma unroll
    for (int v = 0; v < 4; ++v) {
      unsigned long long m = __ballot(e == v);
      if (m != 0ull) {
        int leader = __ffsll((long long)m) - 1;
        int base = 0;
        if (lane == leader) base = atomicAdd(&lc[4 + v], __popcll(m));
        base = __shfl(base, leader);
        if (e == v) {
          int rank = __popcll(m & ((1ull << lane) - 1ull));
          perm[lc[8 + v] + base + rank] = i;
        }
      }
    }
  }
  __syncthreads();
  if (tid < 12) c[tid] = lc[tid];
}

// ---------------- conversions ----------------
__global__ void cvt_f32_bf16(const float* __restrict__ src, u16* __restrict__ dst, long n4) {
  long i = (long)blockIdx.x * blockDim.x + threadIdx.x;
  long stride = (long)gridDim.x * blockDim.x;
  for (; i < n4; i += stride) {
    f32x4 v = ((const f32x4*)src)[i];
    u16x4 o;
    o.x = f2bf(v.x); o.y = f2bf(v.y); o.z = f2bf(v.z); o.w = f2bf(v.w);
    ((u16x4*)dst)[i] = o;
  }
}

// src [z][R][C] f32 -> dst [z][C][R] bf16. Tile 64 src-rows x 32 src-cols;
// ushort2 writes (4B/lane coalesced). LDS reads 2-way conflict = free (m136).
__global__ void transpose_w(const float* __restrict__ src, u16* __restrict__ dst,
                            int R, int C) {
  __shared__ float t[64][33];
  long base = (long)blockIdx.z * R * C;
  int c0 = blockIdx.x * 32, r0 = blockIdx.y * 64;
  int tx = threadIdx.x, ty = threadIdx.y;  // (32,8)
#pragma unroll
  for (int i = 0; i < 64; i += 8)
    t[ty + i][tx] = src[base + (long)(r0 + ty + i) * C + c0 + tx];
  __syncthreads();
#pragma unroll
  for (int j = 0; j < 4; ++j) {
    int cc = ty + 8 * j;  // src col within tile
    ushort2 v;
    v.x = f2bf(t[2 * tx][cc]);
    v.y = f2bf(t[2 * tx + 1][cc]);
    *(ushort2*)&dst[base + (long)(c0 + cc) * R + r0 + 2 * tx] = v;
  }
}

// ======== 256x256 uniform-stage 8-phase / 2-K-tile GEMM (round-9 base) ========
// 512 threads = 8 waves (2M x 4N), per-wave 128x64. BK=64. LDS 128KB.
// Rows 128B, XOR swizzle byte ^= (row&7)<<4 (inverse on global source);
// 0 bank conflicts measured. Stage schedule: P1 Ah1(t+1), P2 Ah0(t+2),
// P3 Bh0(t+2), P4 Bh1(t+2)+vmcnt(6), mirrored for second K-tile.
// Round-16 change: P3's barrier removed (3 bars/K-tile). Audit: S3 needs
// all Bh0(t) reads (P1) -> P2 BAR covers; S4 needs Bh1(t) reads (P2) ->
// P2 BAR + >=770cy land-margin; P3's Ah1(t) reads vs next-tile S1 writes
// separated by P4's VMCNT+BAR; per-wave vmcnt ledger unchanged.

DEV void stageA(const u16* __restrict__ A, long K, long bm, int k0, int g,
                u16* lds, int tid) {
#pragma unroll
  for (int j = 0; j < 2; ++j) {
    int i = j * 512 + tid;
    int row = ((i >> 9) << 7) | (g << 6) | ((i >> 3) & 63);
    int p = (i & 7) * 16;                  // phys byte-in-row
    int ke = (p ^ ((row & 7) << 4)) >> 1;  // logical k element (inverse swizzle)
    async16(A + (bm + row) * K + k0 + ke, lds + row * 64 + (i & 7) * 8);
  }
}

DEV void stageB(const u16* __restrict__ Bt, long K, long bn, int k0, int g,
                u16* lds, int tid) {
#pragma unroll
  for (int j = 0; j < 2; ++j) {
    int i = j * 512 + tid;
    int col = ((i >> 8) << 6) | (g << 5) | ((i >> 3) & 31);
    int p = (i & 7) * 16;
    int ke = (p ^ ((col & 7) << 4)) >> 1;
    async16(Bt + (bn + col) * K + k0 + ke, lds + col * 64 + (i & 7) * 8);
  }
}

// gathered A staging: per-thread global rows preloaded (ar[j]), LDS row from tid
DEV void stageAg(const u16* __restrict__ X, long K, int k0, int g,
                 const long* ar, u16* lds, int tid) {
#pragma unroll
  for (int j = 0; j < 2; ++j) {
    int i = j * 512 + tid;
    int row = (j << 7) | (g << 6) | ((i >> 3) & 63);
    int p = (i & 7) * 16;
    int ke = (p ^ ((row & 7) << 4)) >> 1;
    async16(X + ar[j] * K + k0 + ke, lds + row * 64 + (i & 7) * 8);
  }
}

DEV s16x8 ldfrag(const u16* lds, int row, int ks, int lk) {
  int b = (ks * 64 + lk * 16) ^ ((row & 7) << 4);
  return *(const s16x8*)((const char*)(lds + row * 64) + b);
}

// one K-tile = 4 phases; S1..S4 = per-phase stage statements; 3 bars/tile
#define KT4(Ac, Bc, S1, S2, S3, S4)                                            \
  {                                                                            \
    _Pragma("unroll") for (int m = 0; m < 4; ++m)                              \
      _Pragma("unroll") for (int ks = 0; ks < 2; ++ks)                         \
        aa[m][ks] = ldfrag(Ac, wr * 128 + m * 16 + lr, ks, lk);                \
    _Pragma("unroll") for (int n = 0; n < 2; ++n)                              \
      _Pragma("unroll") for (int ks = 0; ks < 2; ++ks)                         \
        blo[n][ks] = ldfrag(Bc, wc * 64 + n * 16 + lr, ks, lk);                \
    S1;                                                                        \
    BAR();                                                                     \
    __builtin_amdgcn_s_setprio(1);                                             \
    _Pragma("unroll") for (int m = 0; m < 4; ++m)                              \
      _Pragma("unroll") for (int n = 0; n < 2; ++n)                            \
        _Pragma("unroll") for (int ks = 0; ks < 2; ++ks)                       \
          MFMA16(acc[m][n], aa[m][ks], blo[n][ks]);                            \
    __builtin_amdgcn_s_setprio(0);                                             \
    _Pragma("unroll") for (int n = 0; n < 2; ++n)                              \
      _Pragma("unroll") for (int ks = 0; ks < 2; ++ks)                         \
        bhi[n][ks] = ldfrag(Bc, wc * 64 + (n + 2) * 16 + lr, ks, lk);          \
    S2;                                                                        \
    BAR();                                                                     \
    __builtin_amdgcn_s_setprio(1);                                             \
    _Pragma("unroll") for (int m = 0; m < 4; ++m)                              \
      _Pragma("unroll") for (int n = 0; n < 2; ++n)                            \
        _Pragma("unroll") for (int ks = 0; ks < 2; ++ks)                       \
          MFMA16(acc[m][n + 2], aa[m][ks], bhi[n][ks]);                        \
    __builtin_amdgcn_s_setprio(0);                                             \
    _Pragma("unroll") for (int m = 0; m < 4; ++m)                              \
      _Pragma("unroll") for (int ks = 0; ks < 2; ++ks)                         \
        aa[m][ks] = ldfrag(Ac, wr * 128 + (m + 4) * 16 + lr, ks, lk);          \
    S3;                                                                        \
    /* no barrier (round-16): see audit above */                               \
    __builtin_amdgcn_s_setprio(1);                                             \
    _Pragma("unroll") for (int m = 0; m < 4; ++m)                              \
      _Pragma("unroll") for (int n = 0; n < 2; ++n)                            \
        _Pragma("unroll") for (int ks = 0; ks < 2; ++ks)                       \
          MFMA16(acc[m + 4][n], aa[m][ks], blo[n][ks]);                        \
    __builtin_amdgcn_s_setprio(0);                                             \
    S4;                                                                        \
    VMCNT(6);                                                                  \
    BAR();                                                                     \
    __builtin_amdgcn_s_setprio(1);                                             \
    _Pragma("unroll") for (int m = 0; m < 4; ++m)                              \
      _Pragma("unroll") for (int n = 0; n < 2; ++n)                            \
        _Pragma("unroll") for (int ks = 0; ks < 2; ++ks)                       \
          MFMA16(acc[m + 4][n + 2], aa[m][ks], bhi[n][ks]);                    \
    __builtin_amdgcn_s_setprio(0);                                             \
  }

template <int RELU, int OUTF32>
__global__ __launch_bounds__(512, 2) void gemm256p(
    const u16* __restrict__ A, const u16* __restrict__ Bt,
    const float* __restrict__ bias, void* __restrict__ Cout, int N, int K) {
  __shared__ u16 Al[2][256 * 64];
  __shared__ u16 Bl[2][256 * 64];
  const int tid = threadIdx.x;
  const int lane = tid & 63, wid = tid >> 6;
  const int wr = wid >> 2, wc = wid & 3;  // 2 x 4 wave grid
  const int lr = lane & 15, lk = lane >> 4;

  // XCD-aware bijective swizzle (grids all % 8 == 0; guarded)
  const int nby = N >> 8;
  const int nwg = gridDim.x;
  int wg = blockIdx.x;
  if ((nwg & 7) == 0) {
    const int q = nwg >> 3;
    wg = (wg & 7) * q + (wg >> 3);
  }
  const long bm = (long)(wg / nby) << 8;
  const long bn = (long)(wg % nby) << 8;

  const int nt = K >> 6;  // even (>=16) for all K used here
  f32x4 acc[8][4] = {};
  s16x8 aa[4][2], blo[2][2], bhi[2][2];

  // prologue: tile0 fully + tile1 halves Ah0,Bh0,Bh1 (Ah1(1) staged at P1)
  stageA(A, K, bm, 0, 0, Al[0], tid);
  stageB(Bt, K, bn, 0, 0, Bl[0], tid);
  stageB(Bt, K, bn, 0, 1, Bl[0], tid);
  stageA(A, K, bm, 0, 1, Al[0], tid);
  stageA(A, K, bm, 64, 0, Al[1], tid);
  stageB(Bt, K, bn, 64, 0, Bl[1], tid);
  stageB(Bt, K, bn, 64, 1, Bl[1], tid);
  VMCNT(6);  // drains tile0's 8 loads; leaves tile1's 3 halves (steady state)
  BAR();

  const int ni = nt >> 1;
  for (int i2 = 0; i2 < ni; ++i2) {
    const int t0 = 2 * i2;
    const int kn1 = (t0 + 1) << 6;  // fresh stage of Ah1(t+1)
    const int kn2 = ((t0 + 2 < nt) ? t0 + 2 : t0) << 6;       // clamped re-stage
    const int kn3 = ((t0 + 3 < nt) ? t0 + 3 : t0 + 1) << 6;
    KT4(Al[0], Bl[0],
        stageA(A, K, bm, kn1, 1, Al[1], tid),
        stageA(A, K, bm, kn2, 0, Al[0], tid),
        stageB(Bt, K, bn, kn2, 0, Bl[0], tid),
        stageB(Bt, K, bn, kn2, 1, Bl[0], tid));
    KT4(Al[1], Bl[1],
        stageA(A, K, bm, kn2, 1, Al[0], tid),
        stageA(A, K, bm, kn3, 0, Al[1], tid),
        stageB(Bt, K, bn, kn3, 0, Bl[1], tid),
        stageB(Bt, K, bn, kn3, 1, Bl[1], tid));
  }

  // epilogue: bias + activation + store
#pragma unroll
  for (int m = 0; m < 8; ++m) {
    const long r0 = bm + wr * 128 + m * 16 + lk * 4;
#pragma unroll
    for (int n = 0; n < 4; ++n) {
      const long col = bn + wc * 64 + n * 16 + lr;
      const float bv = bias[col];
#pragma unroll
      for (int j = 0; j < 4; ++j) {
        float v = acc[m][n][j] + bv;
        if (RELU) v = fmaxf(v, 0.0f);
        if (OUTF32) ((float*)Cout)[(r0 + j) * (long)N + col] = v;
        else        ((u16*)Cout)[(r0 + j) * (long)N + col] = f2bf(v);
      }
    }
  }
}

// ======== gathered expert GEMM on the same 256x256 8-phase structure ========
__global__ __launch_bounds__(512, 2) void gemm256e(
    const u16* __restrict__ X, const u16* __restrict__ Wt,
    const float* __restrict__ bexp, u16* __restrict__ Out,
    const int* __restrict__ perm, const int* __restrict__ cvec,
    int K, int N, int TPE) {
  __shared__ u16 Al[2][256 * 64];
  __shared__ u16 Bl[2][256 * 64];
  const int e = blockIdx.x / TPE;
  const int tile = blockIdx.x - e * TPE;
  const int cnt = cvec[e];
  if (tile * 256 >= cnt) return;
  const int start = cvec[8 + e];

  const int tid = threadIdx.x;
  const int lane = tid & 63, wid = tid >> 6;
  const int wr = wid >> 2, wc = wid & 3;  // 2M x 4N
  const int lr = lane & 15, lk = lane >> 4;
  const long bn = (long)blockIdx.y << 8;
  const long wbase = (long)e * N;

  // preload gathered A-row indices (fixed per thread)
  long ar[2][2];
#pragma unroll
  for (int g = 0; g < 2; ++g)
#pragma unroll
    for (int j = 0; j < 2; ++j) {
      int rie = tile * 256 + ((j << 7) | (g << 6) | ((tid >> 3) & 63));
      ar[g][j] = perm[start + (rie < cnt - 1 ? rie : cnt - 1)];
    }

  const int nt = K >> 6;  // K=2048 -> 32, even
  f32x4 acc[8][4] = {};
  s16x8 aa[4][2], blo[2][2], bhi[2][2];

  stageAg(X, K, 0, 0, ar[0], Al[0], tid);
  stageB(Wt, K, wbase + bn, 0, 0, Bl[0], tid);
  stageB(Wt, K, wbase + bn, 0, 1, Bl[0], tid);
  stageAg(X, K, 0, 1, ar[1], Al[0], tid);
  stageAg(X, K, 64, 0, ar[0], Al[1], tid);
  stageB(Wt, K, wbase + bn, 64, 0, Bl[1], tid);
  stageB(Wt, K, wbase + bn, 64, 1, Bl[1], tid);
  VMCNT(6);
  BAR();

  const int ni = nt >> 1;
  for (int i2 = 0; i2 < ni; ++i2) {
    const int t0 = 2 * i2;
    const int kn1 = (t0 + 1) << 6;
    const int kn2 = ((t0 + 2 < nt) ? t0 + 2 : t0) << 6;
    const int kn3 = ((t0 + 3 < nt) ? t0 + 3 : t0 + 1) << 6;
    KT4(Al[0], Bl[0],
        stageAg(X, K, kn1, 1, ar[1], Al[1], tid),
        stageAg(X, K, kn2, 0, ar[0], Al[0], tid),
        stageB(Wt, K, wbase + bn, kn2, 0, Bl[0], tid),
        stageB(Wt, K, wbase + bn, kn2, 1, Bl[0], tid));
    KT4(Al[1], Bl[1],
        stageAg(X, K, kn2, 1, ar[1], Al[0], tid),
        stageAg(X, K, kn3, 0, ar[0], Al[1], tid),
        stageB(Wt, K, wbase + bn, kn3, 0, Bl[1], tid),
        stageB(Wt, K, wbase + bn, kn3, 1, Bl[1], tid));
  }

  // epilogue: bias + scatter via perm (guard rb < cnt)
#pragma unroll
  for (int m = 0; m < 8; ++m) {
    const int rb = tile * 256 + wr * 128 + m * 16 + lk * 4;
#pragma unroll
    for (int j = 0; j < 4; ++j) {
      if (rb + j < cnt) {
        const long grow = perm[start + rb + j];
#pragma unroll
        for (int n = 0; n < 4; ++n) {
          const long col = bn + wc * 64 + n * 16 + lr;
          float v = acc[m][n][j] + bexp[wbase + col];
          Out[grow * (long)N + col] = f2bf(v);
        }
      }
    }
  }
}

// ---------------- launch ----------------
extern "C" void kernel_launch(void* const* d_in, const int* in_sizes, int n_in,
                              void* d_out, int out_size, void* d_ws, size_t ws_size,
                              hipStream_t stream) {
  const float* x     = (const float*)d_in[0];
  const int*   kk    = (const int*)d_in[1];
  const float* W_exp = (const float*)d_in[2];
  const float* b_exp = (const float*)d_in[3];
  const float* W1    = (const float*)d_in[4];
  const float* b1    = (const float*)d_in[5];
  const float* W2    = (const float*)d_in[6];
  const float* b2    = (const float*)d_in[7];
  const float* W3    = (const float*)d_in[8];
  const float* b3    = (const float*)d_in[9];
  float* out = (float*)d_out;

  const int B = 16384, DIN = 2048, DC = 1024, H = 4096, DOUT = 1024, E = 4;

  uint8_t* ws = (uint8_t*)d_ws;
  const size_t MB = 1ull << 20;
  u16* xb    = (u16*)(ws + 0);         // 64MB  [B][2048]
  u16* algn  = (u16*)(ws + 64 * MB);   // 32MB  [B][1024]
  u16* h2    = (u16*)(ws + 0);         // 128MB [B][4096] (reuses xb+algn, live later)
  u16* h1    = (u16*)(ws + 128 * MB);  // 128MB [B][4096]
  u16* wexpt = (u16*)(ws + 256 * MB);  // 16MB  [4][1024][2048]
  u16* w1t   = (u16*)(ws + 272 * MB);  // 8MB   [4096][1024]
  u16* w2t   = (u16*)(ws + 280 * MB);  // 32MB  [4096][4096]
  u16* w3t   = (u16*)(ws + 312 * MB);  // 8MB   [1024][4096]
  int* perm  = (int*)(ws + 320 * MB);  // 64KB
  int* cvec  = (int*)(ws + 320 * MB + 65536);

  // fused router (1 launch)
  route_all<<<1, 1024, 0, stream>>>(kk, cvec, perm, B);

  // conversions
  cvt_f32_bf16<<<2048, 256, 0, stream>>>(x, xb, (long)B * DIN / 4);
  dim3 tb(32, 8);
  transpose_w<<<dim3(DC / 32, DIN / 64, E), tb, 0, stream>>>(W_exp, wexpt, DIN, DC);
  transpose_w<<<dim3(H / 32, DC / 64, 1), tb, 0, stream>>>(W1, w1t, DC, H);
  transpose_w<<<dim3(H / 32, H / 64, 1), tb, 0, stream>>>(W2, w2t, H, H);
  transpose_w<<<dim3(DOUT / 32, H / 64, 1), tb, 0, stream>>>(W3, w3t, H, DOUT);

  // expert projection (gathered, 256^2 8-phase, 3-bar KT4)
  const int TPE = B / 256;
  gemm256e<<<dim3(E * TPE, DC / 256), 512, 0, stream>>>(
      xb, wexpt, b_exp, algn, perm, cvec, DIN, DC, TPE);

  // dense MLP (3-bar KT4)
  gemm256p<1, 0><<<dim3((B / 256) * (H / 256)), 512, 0, stream>>>(algn, w1t, b1, h1, H, DC);
  gemm256p<1, 0><<<dim3((B / 256) * (H / 256)), 512, 0, stream>>>(h1, w2t, b2, h2, H, H);
  gemm256p<0, 1><<<dim3((B / 256) * (DOUT / 256)), 512, 0, stream>>>(h2, w3t, b3, out, DOUT, H);
}

// Round 18
// 878.693 us; speedup vs baseline: 1.4251x; 1.0002x over previous
//
#include <hip/hip_runtime.h>
#include <stdint.h>

#define DEV static __device__ __forceinline__

typedef unsigned short u16;
typedef float  f32x4 __attribute__((ext_vector_type(4)));
typedef short  s16x8 __attribute__((ext_vector_type(8)));
typedef u16    u16x4 __attribute__((ext_vector_type(4)));

#define VMCNT(n) asm volatile("s_waitcnt vmcnt(" #n ")" ::: "memory")
#define BAR() __builtin_amdgcn_s_barrier()
#define MFMA16(d, va, vb) d = __builtin_amdgcn_mfma_f32_16x16x32_bf16(va, vb, d, 0, 0, 0)

// round-to-nearest-even f32 -> bf16 bits
DEV u16 f2bf(float f) {
  uint32_t u = __float_as_uint(f);
  u += 0x7FFFu + ((u >> 16) & 1u);
  return (u16)(u >> 16);
}

// async global->LDS, 16 bytes per lane
DEV void async16(const void* g, void* l) {
  __builtin_amdgcn_global_load_lds(
      (const __attribute__((address_space(1))) void*)g,
      (__attribute__((address_space(3))) void*)l, 16, 0, 0);
}

// ---------------- fused router (count+scan+scatter, wave-aggregated) ----------------
// cvec layout: [0..3]=cnt, [4..7]=cursor, [8..11]=start
__global__ __launch_bounds__(1024) void route_all(const int* __restrict__ k,
                                                  int* __restrict__ c,
                                                  int* __restrict__ perm, int B) {
  __shared__ int lc[12];
  const int tid = threadIdx.x;
  const int lane = tid & 63;
  if (tid < 12) lc[tid] = 0;
  __syncthreads();
  // count: one atomic per wave per expert value
  for (int i = tid; i < B; i += 1024) {
    int e = k[i];
#pragma unroll
    for (int v = 0; v < 4; ++v) {
      unsigned long long m = __ballot(e == v);
      if (m != 0ull && lane == __ffsll((long long)m) - 1)
        atomicAdd(&lc[v], __popcll(m));
    }
  }
  __syncthreads();
  if (tid == 0) {
    int s = 0;
    for (int e = 0; e < 4; ++e) { lc[8 + e] = s; s += lc[e]; }
  }
  __syncthreads();
  // scatter: wave-aggregated rank, one atomic per wave per value
  for (int i = tid; i < B; i += 1024) {
    int e = k[i];
#pragma unroll
    for (int v = 0; v < 4; ++v) {
      unsigned long long m = __ballot(e == v);
      if (m != 0ull) {
        int leader = __ffsll((long long)m) - 1;
        int base = 0;
        if (lane == leader) base = atomicAdd(&lc[4 + v], __popcll(m));
        base = __shfl(base, leader);
        if (e == v) {
          int rank = __popcll(m & ((1ull << lane) - 1ull));
          perm[lc[8 + v] + base + rank] = i;
        }
      }
    }
  }
  __syncthreads();
  if (tid < 12) c[tid] = lc[tid];
}

// ---------------- conversions ----------------
__global__ void cvt_f32_bf16(const float* __restrict__ src, u16* __restrict__ dst, long n4) {
  long i = (long)blockIdx.x * blockDim.x + threadIdx.x;
  long stride = (long)gridDim.x * blockDim.x;
  for (; i < n4; i += stride) {
    f32x4 v = ((const f32x4*)src)[i];
    u16x4 o;
    o.x = f2bf(v.x); o.y = f2bf(v.y); o.z = f2bf(v.z); o.w = f2bf(v.w);
    ((u16x4*)dst)[i] = o;
  }
}

// src [z][R][C] f32 -> dst [z][C][R] bf16. Tile 64 src-rows x 32 src-cols;
// ushort2 writes (4B/lane coalesced). LDS reads 2-way conflict = free (m136).
__global__ void transpose_w(const float* __restrict__ src, u16* __restrict__ dst,
                            int R, int C) {
  __shared__ float t[64][33];
  long base = (long)blockIdx.z * R * C;
  int c0 = blockIdx.x * 32, r0 = blockIdx.y * 64;
  int tx = threadIdx.x, ty = threadIdx.y;  // (32,8)
#pragma unroll
  for (int i = 0; i < 64; i += 8)
    t[ty + i][tx] = src[base + (long)(r0 + ty + i) * C + c0 + tx];
  __syncthreads();
#pragma unroll
  for (int j = 0; j < 4; ++j) {
    int cc = ty + 8 * j;  // src col within tile
    ushort2 v;
    v.x = f2bf(t[2 * tx][cc]);
    v.y = f2bf(t[2 * tx + 1][cc]);
    *(ushort2*)&dst[base + (long)(c0 + cc) * R + r0 + 2 * tx] = v;
  }
}

// ======== 256x256 uniform-stage 8-phase / 2-K-tile GEMM (round-16 verified) ========
// 512 threads = 8 waves (2M x 4N), per-wave 128x64. BK=64. LDS 128KB.
// Rows 128B, XOR swizzle byte ^= (row&7)<<4 (inverse on global source);
// 0 bank conflicts measured. Stage schedule: P1 Ah1(t+1), P2 Ah0(t+2),
// P3 Bh0(t+2), P4 Bh1(t+2)+vmcnt(6), mirrored for second K-tile.
// 3 bars/K-tile (P3's removed in round 16 — safe: BAR(P2) separates the
// last blo/bhi read-issue from the S3/S4 overwrite-issue). Round-17's
// attempt to also drop P1's barrier RACED (absmax 0.357): S2 overwrites
// the current buffer's A-h0 with NO barrier between a lagging wave's P1
// aa-reads and the overwrite — pure latency certification across zero
// barriers is not sound. Keep P1's barrier permanently.

DEV void stageA(const u16* __restrict__ A, long K, long bm, int k0, int g,
                u16* lds, int tid) {
#pragma unroll
  for (int j = 0; j < 2; ++j) {
    int i = j * 512 + tid;
    int row = ((i >> 9) << 7) | (g << 6) | ((i >> 3) & 63);
    int p = (i & 7) * 16;                  // phys byte-in-row
    int ke = (p ^ ((row & 7) << 4)) >> 1;  // logical k element (inverse swizzle)
    async16(A + (bm + row) * K + k0 + ke, lds + row * 64 + (i & 7) * 8);
  }
}

DEV void stageB(const u16* __restrict__ Bt, long K, long bn, int k0, int g,
                u16* lds, int tid) {
#pragma unroll
  for (int j = 0; j < 2; ++j) {
    int i = j * 512 + tid;
    int col = ((i >> 8) << 6) | (g << 5) | ((i >> 3) & 31);
    int p = (i & 7) * 16;
    int ke = (p ^ ((col & 7) << 4)) >> 1;
    async16(Bt + (bn + col) * K + k0 + ke, lds + col * 64 + (i & 7) * 8);
  }
}

// gathered A staging: per-thread global rows preloaded (ar[j]), LDS row from tid
DEV void stageAg(const u16* __restrict__ X, long K, int k0, int g,
                 const long* ar, u16* lds, int tid) {
#pragma unroll
  for (int j = 0; j < 2; ++j) {
    int i = j * 512 + tid;
    int row = (j << 7) | (g << 6) | ((i >> 3) & 63);
    int p = (i & 7) * 16;
    int ke = (p ^ ((row & 7) << 4)) >> 1;
    async16(X + ar[j] * K + k0 + ke, lds + row * 64 + (i & 7) * 8);
  }
}

DEV s16x8 ldfrag(const u16* lds, int row, int ks, int lk) {
  int b = (ks * 64 + lk * 16) ^ ((row & 7) << 4);
  return *(const s16x8*)((const char*)(lds + row * 64) + b);
}

// one K-tile = 4 phases; S1..S4 = per-phase stage statements; 3 bars/tile
#define KT4(Ac, Bc, S1, S2, S3, S4)                                            \
  {                                                                            \
    _Pragma("unroll") for (int m = 0; m < 4; ++m)                              \
      _Pragma("unroll") for (int ks = 0; ks < 2; ++ks)                         \
        aa[m][ks] = ldfrag(Ac, wr * 128 + m * 16 + lr, ks, lk);                \
    _Pragma("unroll") for (int n = 0; n < 2; ++n)                              \
      _Pragma("unroll") for (int ks = 0; ks < 2; ++ks)                         \
        blo[n][ks] = ldfrag(Bc, wc * 64 + n * 16 + lr, ks, lk);                \
    S1;                                                                        \
    BAR();                                                                     \
    __builtin_amdgcn_s_setprio(1);                                             \
    _Pragma("unroll") for (int m = 0; m < 4; ++m)                              \
      _Pragma("unroll") for (int n = 0; n < 2; ++n)                            \
        _Pragma("unroll") for (int ks = 0; ks < 2; ++ks)                       \
          MFMA16(acc[m][n], aa[m][ks], blo[n][ks]);                            \
    __builtin_amdgcn_s_setprio(0);                                             \
    _Pragma("unroll") for (int n = 0; n < 2; ++n)                              \
      _Pragma("unroll") for (int ks = 0; ks < 2; ++ks)                         \
        bhi[n][ks] = ldfrag(Bc, wc * 64 + (n + 2) * 16 + lr, ks, lk);          \
    S2;                                                                        \
    BAR();                                                                     \
    __builtin_amdgcn_s_setprio(1);                                             \
    _Pragma("unroll") for (int m = 0; m < 4; ++m)                              \
      _Pragma("unroll") for (int n = 0; n < 2; ++n)                            \
        _Pragma("unroll") for (int ks = 0; ks < 2; ++ks)                       \
          MFMA16(acc[m][n + 2], aa[m][ks], bhi[n][ks]);                        \
    __builtin_amdgcn_s_setprio(0);                                             \
    _Pragma("unroll") for (int m = 0; m < 4; ++m)                              \
      _Pragma("unroll") for (int ks = 0; ks < 2; ++ks)                         \
        aa[m][ks] = ldfrag(Ac, wr * 128 + (m + 4) * 16 + lr, ks, lk);          \
    S3;                                                                        \
    /* no barrier (round-16): covered by BAR(P2) */                            \
    __builtin_amdgcn_s_setprio(1);                                             \
    _Pragma("unroll") for (int m = 0; m < 4; ++m)                              \
      _Pragma("unroll") for (int n = 0; n < 2; ++n)                            \
        _Pragma("unroll") for (int ks = 0; ks < 2; ++ks)                       \
          MFMA16(acc[m + 4][n], aa[m][ks], blo[n][ks]);                        \
    __builtin_amdgcn_s_setprio(0);                                             \
    S4;                                                                        \
    VMCNT(6);                                                                  \
    BAR();                                                                     \
    __builtin_amdgcn_s_setprio(1);                                             \
    _Pragma("unroll") for (int m = 0; m < 4; ++m)                              \
      _Pragma("unroll") for (int n = 0; n < 2; ++n)                            \
        _Pragma("unroll") for (int ks = 0; ks < 2; ++ks)                       \
          MFMA16(acc[m + 4][n + 2], aa[m][ks], bhi[n][ks]);                    \
    __builtin_amdgcn_s_setprio(0);                                             \
  }

template <int RELU, int OUTF32>
__global__ __launch_bounds__(512, 2) void gemm256p(
    const u16* __restrict__ A, const u16* __restrict__ Bt,
    const float* __restrict__ bias, void* __restrict__ Cout, int N, int K) {
  __shared__ u16 Al[2][256 * 64];
  __shared__ u16 Bl[2][256 * 64];
  const int tid = threadIdx.x;
  const int lane = tid & 63, wid = tid >> 6;
  const int wr = wid >> 2, wc = wid & 3;  // 2 x 4 wave grid
  const int lr = lane & 15, lk = lane >> 4;

  // XCD-aware bijective swizzle (grids all % 8 == 0; guarded)
  const int nby = N >> 8;
  const int nwg = gridDim.x;
  int wg = blockIdx.x;
  if ((nwg & 7) == 0) {
    const int q = nwg >> 3;
    wg = (wg & 7) * q + (wg >> 3);
  }
  const long bm = (long)(wg / nby) << 8;
  const long bn = (long)(wg % nby) << 8;

  const int nt = K >> 6;  // even (>=16) for all K used here
  f32x4 acc[8][4] = {};
  s16x8 aa[4][2], blo[2][2], bhi[2][2];

  // prologue: tile0 fully + tile1 halves Ah0,Bh0,Bh1 (Ah1(1) staged at P1)
  stageA(A, K, bm, 0, 0, Al[0], tid);
  stageB(Bt, K, bn, 0, 0, Bl[0], tid);
  stageB(Bt, K, bn, 0, 1, Bl[0], tid);
  stageA(A, K, bm, 0, 1, Al[0], tid);
  stageA(A, K, bm, 64, 0, Al[1], tid);
  stageB(Bt, K, bn, 64, 0, Bl[1], tid);
  stageB(Bt, K, bn, 64, 1, Bl[1], tid);
  VMCNT(6);  // drains tile0's 8 loads; leaves tile1's 3 halves (steady state)
  BAR();

  const int ni = nt >> 1;
  for (int i2 = 0; i2 < ni; ++i2) {
    const int t0 = 2 * i2;
    const int kn1 = (t0 + 1) << 6;  // fresh stage of Ah1(t+1)
    const int kn2 = ((t0 + 2 < nt) ? t0 + 2 : t0) << 6;       // clamped re-stage
    const int kn3 = ((t0 + 3 < nt) ? t0 + 3 : t0 + 1) << 6;
    KT4(Al[0], Bl[0],
        stageA(A, K, bm, kn1, 1, Al[1], tid),
        stageA(A, K, bm, kn2, 0, Al[0], tid),
        stageB(Bt, K, bn, kn2, 0, Bl[0], tid),
        stageB(Bt, K, bn, kn2, 1, Bl[0], tid));
    KT4(Al[1], Bl[1],
        stageA(A, K, bm, kn2, 1, Al[0], tid),
        stageA(A, K, bm, kn3, 0, Al[1], tid),
        stageB(Bt, K, bn, kn3, 0, Bl[1], tid),
        stageB(Bt, K, bn, kn3, 1, Bl[1], tid));
  }

  // epilogue: bias + activation + store
#pragma unroll
  for (int m = 0; m < 8; ++m) {
    const long r0 = bm + wr * 128 + m * 16 + lk * 4;
#pragma unroll
    for (int n = 0; n < 4; ++n) {
      const long col = bn + wc * 64 + n * 16 + lr;
      const float bv = bias[col];
#pragma unroll
      for (int j = 0; j < 4; ++j) {
        float v = acc[m][n][j] + bv;
        if (RELU) v = fmaxf(v, 0.0f);
        if (OUTF32) ((float*)Cout)[(r0 + j) * (long)N + col] = v;
        else        ((u16*)Cout)[(r0 + j) * (long)N + col] = f2bf(v);
      }
    }
  }
}

// ======== gathered expert GEMM on the same 256x256 8-phase structure ========
__global__ __launch_bounds__(512, 2) void gemm256e(
    const u16* __restrict__ X, const u16* __restrict__ Wt,
    const float* __restrict__ bexp, u16* __restrict__ Out,
    const int* __restrict__ perm, const int* __restrict__ cvec,
    int K, int N, int TPE) {
  __shared__ u16 Al[2][256 * 64];
  __shared__ u16 Bl[2][256 * 64];
  const int e = blockIdx.x / TPE;
  const int tile = blockIdx.x - e * TPE;
  const int cnt = cvec[e];
  if (tile * 256 >= cnt) return;
  const int start = cvec[8 + e];

  const int tid = threadIdx.x;
  const int lane = tid & 63, wid = tid >> 6;
  const int wr = wid >> 2, wc = wid & 3;  // 2M x 4N
  const int lr = lane & 15, lk = lane >> 4;
  const long bn = (long)blockIdx.y << 8;
  const long wbase = (long)e * N;

  // preload gathered A-row indices (fixed per thread)
  long ar[2][2];
#pragma unroll
  for (int g = 0; g < 2; ++g)
#pragma unroll
    for (int j = 0; j < 2; ++j) {
      int rie = tile * 256 + ((j << 7) | (g << 6) | ((tid >> 3) & 63));
      ar[g][j] = perm[start + (rie < cnt - 1 ? rie : cnt - 1)];
    }

  const int nt = K >> 6;  // K=2048 -> 32, even
  f32x4 acc[8][4] = {};
  s16x8 aa[4][2], blo[2][2], bhi[2][2];

  stageAg(X, K, 0, 0, ar[0], Al[0], tid);
  stageB(Wt, K, wbase + bn, 0, 0, Bl[0], tid);
  stageB(Wt, K, wbase + bn, 0, 1, Bl[0], tid);
  stageAg(X, K, 0, 1, ar[1], Al[0], tid);
  stageAg(X, K, 64, 0, ar[0], Al[1], tid);
  stageB(Wt, K, wbase + bn, 64, 0, Bl[1], tid);
  stageB(Wt, K, wbase + bn, 64, 1, Bl[1], tid);
  VMCNT(6);
  BAR();

  const int ni = nt >> 1;
  for (int i2 = 0; i2 < ni; ++i2) {
    const int t0 = 2 * i2;
    const int kn1 = (t0 + 1) << 6;
    const int kn2 = ((t0 + 2 < nt) ? t0 + 2 : t0) << 6;
    const int kn3 = ((t0 + 3 < nt) ? t0 + 3 : t0 + 1) << 6;
    KT4(Al[0], Bl[0],
        stageAg(X, K, kn1, 1, ar[1], Al[1], tid),
        stageAg(X, K, kn2, 0, ar[0], Al[0], tid),
        stageB(Wt, K, wbase + bn, kn2, 0, Bl[0], tid),
        stageB(Wt, K, wbase + bn, kn2, 1, Bl[0], tid));
    KT4(Al[1], Bl[1],
        stageAg(X, K, kn2, 1, ar[1], Al[0], tid),
        stageAg(X, K, kn3, 0, ar[0], Al[1], tid),
        stageB(Wt, K, wbase + bn, kn3, 0, Bl[1], tid),
        stageB(Wt, K, wbase + bn, kn3, 1, Bl[1], tid));
  }

  // epilogue: bias + scatter via perm (guard rb < cnt)
#pragma unroll
  for (int m = 0; m < 8; ++m) {
    const int rb = tile * 256 + wr * 128 + m * 16 + lk * 4;
#pragma unroll
    for (int j = 0; j < 4; ++j) {
      if (rb + j < cnt) {
        const long grow = perm[start + rb + j];
#pragma unroll
        for (int n = 0; n < 4; ++n) {
          const long col = bn + wc * 64 + n * 16 + lr;
          float v = acc[m][n][j] + bexp[wbase + col];
          Out[grow * (long)N + col] = f2bf(v);
        }
      }
    }
  }
}

// ---------------- launch ----------------
extern "C" void kernel_launch(void* const* d_in, const int* in_sizes, int n_in,
                              void* d_out, int out_size, void* d_ws, size_t ws_size,
                              hipStream_t stream) {
  const float* x     = (const float*)d_in[0];
  const int*   kk    = (const int*)d_in[1];
  const float* W_exp = (const float*)d_in[2];
  const float* b_exp = (const float*)d_in[3];
  const float* W1    = (const float*)d_in[4];
  const float* b1    = (const float*)d_in[5];
  const float* W2    = (const float*)d_in[6];
  const float* b2    = (const float*)d_in[7];
  const float* W3    = (const float*)d_in[8];
  const float* b3    = (const float*)d_in[9];
  float* out = (float*)d_out;

  const int B = 16384, DIN = 2048, DC = 1024, H = 4096, DOUT = 1024, E = 4;

  uint8_t* ws = (uint8_t*)d_ws;
  const size_t MB = 1ull << 20;
  u16* xb    = (u16*)(ws + 0);         // 64MB  [B][2048]
  u16* algn  = (u16*)(ws + 64 * MB);   // 32MB  [B][1024]
  u16* h2    = (u16*)(ws + 0);         // 128MB [B][4096] (reuses xb+algn, live later)
  u16* h1    = (u16*)(ws + 128 * MB);  // 128MB [B][4096]
  u16* wexpt = (u16*)(ws + 256 * MB);  // 16MB  [4][1024][2048]
  u16* w1t   = (u16*)(ws + 272 * MB);  // 8MB   [4096][1024]
  u16* w2t   = (u16*)(ws + 280 * MB);  // 32MB  [4096][4096]
  u16* w3t   = (u16*)(ws + 312 * MB);  // 8MB   [1024][4096]
  int* perm  = (int*)(ws + 320 * MB);  // 64KB
  int* cvec  = (int*)(ws + 320 * MB + 65536);

  // fused router (1 launch)
  route_all<<<1, 1024, 0, stream>>>(kk, cvec, perm, B);

  // conversions
  cvt_f32_bf16<<<2048, 256, 0, stream>>>(x, xb, (long)B * DIN / 4);
  dim3 tb(32, 8);
  transpose_w<<<dim3(DC / 32, DIN / 64, E), tb, 0, stream>>>(W_exp, wexpt, DIN, DC);
  transpose_w<<<dim3(H / 32, DC / 64, 1), tb, 0, stream>>>(W1, w1t, DC, H);
  transpose_w<<<dim3(H / 32, H / 64, 1), tb, 0, stream>>>(W2, w2t, H, H);
  transpose_w<<<dim3(DOUT / 32, H / 64, 1), tb, 0, stream>>>(W3, w3t, H, DOUT);

  // expert projection (gathered, 256^2 8-phase, 3-bar KT4)
  const int TPE = B / 256;
  gemm256e<<<dim3(E * TPE, DC / 256), 512, 0, stream>>>(
      xb, wexpt, b_exp, algn, perm, cvec, DIN, DC, TPE);

  // dense MLP (3-bar KT4)
  gemm256p<1, 0><<<dim3((B / 256) * (H / 256)), 512, 0, stream>>>(algn, w1t, b1, h1, H, DC);
  gemm256p<1, 0><<<dim3((B / 256) * (H / 256)), 512, 0, stream>>>(h1, w2t, b2, h2, H, H);
  gemm256p<0, 1><<<dim3((B / 256) * (DOUT / 256)), 512, 0, stream>>>(h2, w3t, b3, out, DOUT, H);
}